// Round 19
// baseline (205.663 us; speedup 1.0000x reference)
//
#include <hip/hip_runtime.h>

// Problem constants (B=8, T=1, H=56, C=512, nh=8, d=64)
// Inputs: float32. Output: float32. ws intermediates: bf16.
#define NH    8
#define DH    64
#define NTOK  3137      // 56*56+1
#define NOUT  785       // 28*28+1
#define CDIM  512
#define ROWS  6280      // 8*785
#define HO    28
#define HIN   56
#define NKT   13        // ceil(785/64) key tiles
#define RELD  55        // 2*(56//2)-1
#define LOG2E 1.4426950408889634f

typedef unsigned short u16;
typedef unsigned int u32;
typedef __attribute__((ext_vector_type(8))) short bf16x8;   // 8 bf16 = 4 VGPRs
typedef __attribute__((ext_vector_type(4))) float f32x4;    // MFMA C/D

__device__ __forceinline__ float b2f(u16 u) { return __uint_as_float(((u32)u) << 16); }
__device__ __forceinline__ u16 f2b(float f) {
  u32 u = __float_as_uint(f);
  return (u16)((u + 0x7FFFu + ((u >> 16) & 1u)) >> 16);
}

// ---------------------------------------------------------------------------
// Kernel 1: depthwise 3x3 stride-2 pool + LayerNorm(64), float4-vectorized.
// (verified R14)
// ---------------------------------------------------------------------------
__global__ __launch_bounds__(256) void pool_ln_kernel(
    const float* __restrict__ x, const float* __restrict__ xr,
    const float* __restrict__ cwq, const float* __restrict__ cwk, const float* __restrict__ cwv,
    const float* __restrict__ gq, const float* __restrict__ bq,
    const float* __restrict__ gk, const float* __restrict__ bk,
    const float* __restrict__ gv, const float* __restrict__ bv,
    u16* __restrict__ Pq, u16* __restrict__ Pk, u16* __restrict__ Pv)
{
  int tid   = threadIdx.x;
  int n     = blockIdx.x * 2 + (tid >> 7);           // token (wave-uniform half)
  int b     = blockIdx.y;
  int which = blockIdx.z;                            // 0=q(x), 1=k+v(x_ref)
  if (n >= NOUT) return;
  int c4 = tid & 127;
  int c  = c4 * 4;
  int d0 = c & 63;

  const float* src  = which ? xr : x;
  const float* srcb = src + (size_t)b * NTOK * CDIM + c;
  size_t obase = (size_t)(b * NOUT + n) * CDIM + c;

  float4 vq = make_float4(0.f, 0.f, 0.f, 0.f);
  float4 vk = make_float4(0.f, 0.f, 0.f, 0.f);
  const float* cw0 = which ? cwk : cwq;

  if (n == 0) {
    float4 t = *(const float4*)(srcb);
    vq = t; vk = t;
  } else {
    int oy = (n - 1) / HO, ox = (n - 1) % HO;
#pragma unroll
    for (int ky = 0; ky < 3; ++ky) {
      int iy = oy * 2 - 1 + ky;
      if (iy < 0 || iy >= HIN) continue;
#pragma unroll
      for (int kx = 0; kx < 3; ++kx) {
        int ix = ox * 2 - 1 + kx;
        if (ix < 0 || ix >= HIN) continue;
        int tok = 1 + iy * HIN + ix;
        float4 t  = *(const float4*)(srcb + (size_t)tok * CDIM);
        float4 w0 = *(const float4*)(cw0 + (ky * 3 + kx) * DH + d0);
        vq.x += t.x * w0.x; vq.y += t.y * w0.y; vq.z += t.z * w0.z; vq.w += t.w * w0.w;
        if (which) {
          float4 w1 = *(const float4*)(cwv + (ky * 3 + kx) * DH + d0);
          vk.x += t.x * w1.x; vk.y += t.y * w1.y; vk.z += t.z * w1.z; vk.w += t.w * w1.w;
        }
      }
    }
  }

  {
    float s  = vq.x + vq.y + vq.z + vq.w;
    float sq = vq.x * vq.x + vq.y * vq.y + vq.z * vq.z + vq.w * vq.w;
#pragma unroll
    for (int off = 1; off < 16; off <<= 1) {
      s  += __shfl_xor(s, off, 64);
      sq += __shfl_xor(sq, off, 64);
    }
    float mu  = s * (1.f / 64.f);
    float var = sq * (1.f / 64.f) - mu * mu;
    float inv = rsqrtf(var + 1e-5f);
    const float* g  = which ? gk : gq;
    const float* be = which ? bk : bq;
    float4 gg = *(const float4*)(g + d0);
    float4 bb = *(const float4*)(be + d0);
    ushort4 o;
    o.x = f2b((vq.x - mu) * inv * gg.x + bb.x);
    o.y = f2b((vq.y - mu) * inv * gg.y + bb.y);
    o.z = f2b((vq.z - mu) * inv * gg.z + bb.z);
    o.w = f2b((vq.w - mu) * inv * gg.w + bb.w);
    *(ushort4*)(((which ? Pk : Pq)) + obase) = o;
  }
  if (which) {
    float s  = vk.x + vk.y + vk.z + vk.w;
    float sq = vk.x * vk.x + vk.y * vk.y + vk.z * vk.z + vk.w * vk.w;
#pragma unroll
    for (int off = 1; off < 16; off <<= 1) {
      s  += __shfl_xor(s, off, 64);
      sq += __shfl_xor(sq, off, 64);
    }
    float mu  = s * (1.f / 64.f);
    float var = sq * (1.f / 64.f) - mu * mu;
    float inv = rsqrtf(var + 1e-5f);
    float4 gg = *(const float4*)(gv + d0);
    float4 bb = *(const float4*)(bv + d0);
    ushort4 o;
    o.x = f2b((vk.x - mu) * inv * gg.x + bb.x);
    o.y = f2b((vk.y - mu) * inv * gg.y + bb.y);
    o.z = f2b((vk.z - mu) * inv * gg.z + bb.z);
    o.w = f2b((vk.w - mu) * inv * gg.w + bb.w);
    *(ushort4*)(Pv + obase) = o;
  }
}

// ---------------------------------------------------------------------------
// Kernel 2: fused conversion. Blocks [0,1024): four 512x512 f32 weights ->
// bf16. Block 1024: rel_pos -> bf16 padded [64][64], pre-scaled by log2e.
// ---------------------------------------------------------------------------
__global__ __launch_bounds__(256) void cvt_kernel(
    const float* __restrict__ W0, const float* __restrict__ W1,
    const float* __restrict__ W2, const float* __restrict__ W3,
    const float* __restrict__ rph, const float* __restrict__ rpw,
    u16* __restrict__ out, u16* __restrict__ Rhb, u16* __restrict__ Rwb)
{
  if (blockIdx.x < 1024) {
    int idx = blockIdx.x * 256 + threadIdx.x;
    const int per = CDIM * CDIM / 4;
    int mat = idx / per, off = (idx - mat * per) * 4;
    const float* src = (mat == 0) ? W0 : (mat == 1) ? W1 : (mat == 2) ? W2 : W3;
    float4 v = *(const float4*)(src + off);
    ushort4 o;
    o.x = f2b(v.x); o.y = f2b(v.y); o.z = f2b(v.z); o.w = f2b(v.w);
    *(ushort4*)(out + (size_t)mat * (CDIM * CDIM) + off) = o;
  } else {
    for (int idx = threadIdx.x; idx < 2 * 64 * 64; idx += 256) {
      int which = idx >> 12, e = idx & 4095;
      int r = e >> 6, d = e & 63;
      u16 v = 0;
      if (r < RELD) {
        const float* rp = which ? rpw : rph;
        v = f2b(rp[r * DH + d] * LOG2E);
      }
      (which ? Rwb : Rhb)[e] = v;
    }
  }
}

// ---------------------------------------------------------------------------
// Kernel 3a: batched MFMA GEMM for q/k/v. Tile 64x128 (wave 32x64).
// (R15 form — no unroll pragma; unroll-4 measured −7 us total in R18.)
// ---------------------------------------------------------------------------
__global__ __launch_bounds__(256) void mgemm3_kernel(
    const u16* __restrict__ Xq, const u16* __restrict__ Xk, const u16* __restrict__ Xv,
    const u16* __restrict__ Wb, const float* __restrict__ bq,
    const float* __restrict__ bk, const float* __restrict__ bv,
    u16* __restrict__ Yq, u16* __restrict__ Yk, u16* __restrict__ Yv)
{
  int z = blockIdx.z;
  const u16* X = (z == 0) ? Xq : (z == 1) ? Xk : Xv;
  const u16* W = Wb + (size_t)z * CDIM * CDIM;
  const float* bias = (z == 0) ? bq : (z == 1) ? bk : bv;
  u16* Y = (z == 0) ? Yq : (z == 1) ? Yk : Yv;

  int tid = threadIdx.x;
  int w = tid >> 6, lane = tid & 63, l15 = lane & 15, lg = lane >> 4;
  int m0 = blockIdx.x * 64 + (w >> 1) * 32;
  int n0 = blockIdx.y * 128 + (w & 1) * 64;

  f32x4 acc[2][4] = {};
  float bs[4];
#pragma unroll
  for (int nf = 0; nf < 4; ++nf) bs[nf] = bias[n0 + nf * 16 + l15];

  for (int k0 = 0; k0 < CDIM; k0 += 32) {
    bf16x8 a[2], b[4];
#pragma unroll
    for (int mf = 0; mf < 2; ++mf) {
      int r = m0 + mf * 16 + l15;
      if (r > ROWS - 1) r = ROWS - 1;
      a[mf] = *(const bf16x8*)(X + (size_t)r * CDIM + k0 + lg * 8);
    }
#pragma unroll
    for (int nf = 0; nf < 4; ++nf) {
      int co = n0 + nf * 16 + l15;
      b[nf] = *(const bf16x8*)(W + (size_t)co * CDIM + k0 + lg * 8);
    }
#pragma unroll
    for (int mf = 0; mf < 2; ++mf)
#pragma unroll
      for (int nf = 0; nf < 4; ++nf)
        acc[mf][nf] = __builtin_amdgcn_mfma_f32_16x16x32_bf16(a[mf], b[nf], acc[mf][nf], 0, 0, 0);
  }

#pragma unroll
  for (int mf = 0; mf < 2; ++mf) {
#pragma unroll
    for (int j = 0; j < 4; ++j) {
      int r = m0 + mf * 16 + lg * 4 + j;
      if (r >= ROWS) continue;
      int bb = r / NOUT, n = r % NOUT;
#pragma unroll
      for (int nf = 0; nf < 4; ++nf) {
        int co = n0 + nf * 16 + l15;
        float v = acc[mf][nf][j] + bs[nf];
        Y[(((size_t)bb * NH + (co >> 6)) * NOUT + n) * DH + (co & 63)] = f2b(v);
      }
    }
  }
}

// ---------------------------------------------------------------------------
// Kernel 3b: proj MFMA GEMM, 64x128 tile -> f32 row-major d_out. (R15 form)
// ---------------------------------------------------------------------------
__global__ __launch_bounds__(256) void mgemm_proj_kernel(
    const u16* __restrict__ X, const u16* __restrict__ Wb, const float* __restrict__ bias,
    float* __restrict__ Y)
{
  int tid = threadIdx.x;
  int w = tid >> 6, lane = tid & 63, l15 = lane & 15, lg = lane >> 4;
  int m0 = blockIdx.x * 64 + (w >> 1) * 32;
  int n0 = blockIdx.y * 128 + (w & 1) * 64;

  f32x4 acc[2][4] = {};
  float bs[4];
#pragma unroll
  for (int nf = 0; nf < 4; ++nf) bs[nf] = bias[n0 + nf * 16 + l15];

  for (int k0 = 0; k0 < CDIM; k0 += 32) {
    bf16x8 a[2], b[4];
#pragma unroll
    for (int mf = 0; mf < 2; ++mf) {
      int r = m0 + mf * 16 + l15;
      if (r > ROWS - 1) r = ROWS - 1;
      a[mf] = *(const bf16x8*)(X + (size_t)r * CDIM + k0 + lg * 8);
    }
#pragma unroll
    for (int nf = 0; nf < 4; ++nf) {
      int co = n0 + nf * 16 + l15;
      b[nf] = *(const bf16x8*)(Wb + (size_t)co * CDIM + k0 + lg * 8);
    }
#pragma unroll
    for (int mf = 0; mf < 2; ++mf)
#pragma unroll
      for (int nf = 0; nf < 4; ++nf)
        acc[mf][nf] = __builtin_amdgcn_mfma_f32_16x16x32_bf16(a[mf], b[nf], acc[mf][nf], 0, 0, 0);
  }

#pragma unroll
  for (int mf = 0; mf < 2; ++mf) {
#pragma unroll
    for (int j = 0; j < 4; ++j) {
      int r = m0 + mf * 16 + lg * 4 + j;
      if (r >= ROWS) continue;
#pragma unroll
      for (int nf = 0; nf < 4; ++nf) {
        int co = n0 + nf * 16 + l15;
        Y[(size_t)r * CDIM + co] = acc[mf][nf][j] + bs[nf];
      }
    }
  }
}

// ---------------------------------------------------------------------------
// Kernel 4: flash-style MFMA attention — EXACT R15 structure (verified 80 us,
// no spill): per-tile K loads before V prefetch, packed-u32 V stage,
// setprio around MFMA clusters, exp2-domain softmax, deferred l-reduce.
// ---------------------------------------------------------------------------
__global__ __launch_bounds__(256, 4) void fattn_kernel(
    const u16* __restrict__ Q, const u16* __restrict__ K, const u16* __restrict__ V,
    const u16* __restrict__ Rhb, const u16* __restrict__ Rwb,
    u16* __restrict__ O)
{
  __shared__ u16 Vs[2][64][64];     // [buf][d][k] XOR-swizzled      16384 B
  __shared__ u16 Ps[4][16][72];     // per-wave P bounce              9216 B
  __shared__ u16 relh[64][RELD];    // G_h[q][r]  (log2e-scaled)      7040 B
  __shared__ u16 relw[64][RELD];    //                                7040 B

  int bid = blockIdx.x;
  int nbid = (bid & 7) * 104 + (bid >> 3);
  int bh = nbid / NKT, qt = nbid % NKT;

  int tid = threadIdx.x;
  int w = tid >> 6, lane = tid & 63, l15 = lane & 15, lg = lane >> 4;
  size_t base = (size_t)bh * NOUT * DH;
  int q0 = qt * 64;

  // V-stage geometry: thread <-> (key pair, 8-d block)
  int vkp = (tid & 31) * 2;         // even key in tile (0..62)
  int vdb = (tid >> 5) * 8;         // d0 (0..56)

  // ---- Q A-fragments direct from global ----
  int qrow_qi = min(q0 + w * 16 + l15, NOUT - 1);
  const u16* qp = Q + base + (size_t)qrow_qi * DH + lg * 8;
  bf16x8 qa0 = *(const bf16x8*)(qp);
  bf16x8 qa1 = *(const bf16x8*)(qp + 32);

  // ---- prologue V stage: tile 0 -> Vs[0] (packed u32 writes) ----
  {
    int ke = min(vkp, NOUT - 1), ko = min(vkp + 1, NOUT - 1);
    bf16x8 ve = *(const bf16x8*)(V + base + (size_t)ke * DH + vdb);
    bf16x8 vo = *(const bf16x8*)(V + base + (size_t)ko * DH + vdb);
#pragma unroll
    for (int i = 0; i < 8; ++i) {
      int d = vdb + i;
      int col = ((((vkp >> 3) ^ (d & 7)) << 3) | (vkp & 7));
      u32 pk = (u32)(u16)ve[i] | ((u32)(u16)vo[i] << 16);
      *(u32*)&Vs[0][d][col] = pk;
    }
  }

  // ---- rel-pos tables via MFMA (wave-private rows, log2e-scaled) ----
#pragma unroll
  for (int nf = 0; nf < 4; ++nf) {
    int rr = nf * 16 + l15;
    const u16* hp = Rhb + rr * 64 + lg * 8;
    bf16x8 hb0 = *(const bf16x8*)(hp);
    bf16x8 hb1 = *(const bf16x8*)(hp + 32);
    f32x4 ah = {};
    ah = __builtin_amdgcn_mfma_f32_16x16x32_bf16(qa0, hb0, ah, 0, 0, 0);
    ah = __builtin_amdgcn_mfma_f32_16x16x32_bf16(qa1, hb1, ah, 0, 0, 0);
    const u16* wp = Rwb + rr * 64 + lg * 8;
    bf16x8 wb0 = *(const bf16x8*)(wp);
    bf16x8 wb1 = *(const bf16x8*)(wp + 32);
    f32x4 aw = {};
    aw = __builtin_amdgcn_mfma_f32_16x16x32_bf16(qa0, wb0, aw, 0, 0, 0);
    aw = __builtin_amdgcn_mfma_f32_16x16x32_bf16(qa1, wb1, aw, 0, 0, 0);
    if (rr < RELD) {
#pragma unroll
      for (int j = 0; j < 4; ++j) {
        relh[w * 16 + lg * 4 + j][rr] = f2b(ah[j]);
        relw[w * 16 + lg * 4 + j][rr] = f2b(aw[j]);
      }
    }
  }

  // ---- per-j query geometry ----
  int qy_j[4], qx_j[4];
  bool qv_j[4];
#pragma unroll
  for (int j = 0; j < 4; ++j) {
    int qi = q0 + w * 16 + lg * 4 + j;
    qv_j[j] = (qi >= 1);
    int qm1 = qi - 1;
    qy_j[j] = qm1 / HO;
    qx_j[j] = qm1 % HO;
  }

  // ---- incremental key geometry per sub ----
  int kyr[4], kxr[4];
#pragma unroll
  for (int sub = 0; sub < 4; ++sub) {
    int km1 = sub * 16 + l15 - 1;   // -1 only for (sub=0,l15=0): unused (key<1)
    kyr[sub] = km1 / HO;
    kxr[sub] = km1 % HO;
  }

  f32x4 o0 = {}, o1 = {}, o2 = {}, o3 = {};
  float mrow[4], lrow[4];
#pragma unroll
  for (int j = 0; j < 4; ++j) { mrow[j] = -1e30f; lrow[j] = 0.f; }

  const float QKSCALE = 0.125f * LOG2E;

  for (int t = 0; t < NKT; ++t) {
    int k0 = t * 64;
    int cur = t & 1;
    __syncthreads();   // Vs[cur] fully staged; prev tile's PV reads done

    // ---- K fragment loads FIRST (oldest in vm queue) ----
    bf16x8 kb[4][2];
#pragma unroll
    for (int sub = 0; sub < 4; ++sub) {
      int key = k0 + sub * 16 + l15;
      int keff = min(key, NOUT - 1);
      const u16* kp = K + base + (size_t)keff * DH + lg * 8;
      kb[sub][0] = *(const bf16x8*)(kp);
      kb[sub][1] = *(const bf16x8*)(kp + 32);
    }

    // ---- THEN issue next V tile's loads ----
    bf16x8 nve, nvo;
    bool have_next = (t + 1 < NKT);
    if (have_next) {
      int ke = min(k0 + 64 + vkp, NOUT - 1), ko = min(k0 + 64 + vkp + 1, NOUT - 1);
      nve = *(const bf16x8*)(V + base + (size_t)ke * DH + vdb);
      nvo = *(const bf16x8*)(V + base + (size_t)ko * DH + vdb);
    }

    // ---- S = scale*Q.K^T + bias   (log2 domain) ----
    f32x4 s[4];
    __builtin_amdgcn_s_setprio(1);
#pragma unroll
    for (int sub = 0; sub < 4; ++sub) {
      f32x4 acc = {};
      acc = __builtin_amdgcn_mfma_f32_16x16x32_bf16(qa0, kb[sub][0], acc, 0, 0, 0);
      acc = __builtin_amdgcn_mfma_f32_16x16x32_bf16(qa1, kb[sub][1], acc, 0, 0, 0);
      s[sub] = acc;
    }
    __builtin_amdgcn_s_setprio(0);
#pragma unroll
    for (int sub = 0; sub < 4; ++sub) {
      int key = k0 + sub * 16 + l15;
      bool kv = key < NOUT;
      int ky = kyr[sub], kx = kxr[sub];
#pragma unroll
      for (int j = 0; j < 4; ++j) {
        float v = s[sub][j] * QKSCALE;
        if (key >= 1 && kv && qv_j[j]) {
          int ql = w * 16 + lg * 4 + j;
          v += b2f(relh[ql][qy_j[j] - ky + 27]) + b2f(relw[ql][qx_j[j] - kx + 27]);
        }
        if (!kv) v = -1e30f;
        s[sub][j] = v;
      }
    }

    // ---- advance key geometry (+64 keys = +2 rows +8 cols, carry) ----
#pragma unroll
    for (int sub = 0; sub < 4; ++sub) {
      kxr[sub] += 8; kyr[sub] += 2;
      if (kxr[sub] >= HO) { kxr[sub] -= HO; kyr[sub] += 1; }
    }

    // ---- online softmax (exp2 domain; per-lane l partials) ----
#pragma unroll
    for (int j = 0; j < 4; ++j) {
      float lm = fmaxf(fmaxf(s[0][j], s[1][j]), fmaxf(s[2][j], s[3][j]));
      lm = fmaxf(lm, __shfl_xor(lm, 1));
      lm = fmaxf(lm, __shfl_xor(lm, 2));
      lm = fmaxf(lm, __shfl_xor(lm, 4));
      lm = fmaxf(lm, __shfl_xor(lm, 8));
      if (lm > mrow[j]) {
        float a = exp2f(mrow[j] - lm);
        mrow[j] = lm;
        o0[j] *= a; o1[j] *= a; o2[j] *= a; o3[j] *= a;
        lrow[j] *= a;
      }
      float ps = 0.f;
#pragma unroll
      for (int sub = 0; sub < 4; ++sub) {
        float pv = exp2f(s[sub][j] - mrow[j]);
        s[sub][j] = pv;
        ps += pv;
      }
      lrow[j] += ps;
    }

    // ---- write next V tile into idle buffer (packed u32; no barrier) ----
    if (have_next) {
#pragma unroll
      for (int i = 0; i < 8; ++i) {
        int d = vdb + i;
        int col = ((((vkp >> 3) ^ (d & 7)) << 3) | (vkp & 7));
        u32 pk = (u32)(u16)nve[i] | ((u32)(u16)nvo[i] << 16);
        *(u32*)&Vs[cur ^ 1][d][col] = pk;
      }
    }

    // ---- bounce P (wave-private) ----
#pragma unroll
    for (int j = 0; j < 4; ++j) {
      Ps[w][lg * 4 + j][ 0 + l15] = f2b(s[0][j]);
      Ps[w][lg * 4 + j][16 + l15] = f2b(s[1][j]);
      Ps[w][lg * 4 + j][32 + l15] = f2b(s[2][j]);
      Ps[w][lg * 4 + j][48 + l15] = f2b(s[3][j]);
    }

    // ---- O += P.V from Vs[cur] ----
    bf16x8 pa0 = *(const bf16x8*)&Ps[w][l15][lg * 8];
    bf16x8 pa1 = *(const bf16x8*)&Ps[w][l15][32 + lg * 8];
    bf16x8 vb00, vb01, vb10, vb11, vb20, vb21, vb30, vb31;
    {
      int r = 0 + l15;
      vb00 = *(const bf16x8*)&Vs[cur][r][((lg ^ (r & 7)) << 3)];
      vb01 = *(const bf16x8*)&Vs[cur][r][(((4 + lg) ^ (r & 7)) << 3)];
    }
    {
      int r = 16 + l15;
      vb10 = *(const bf16x8*)&Vs[cur][r][((lg ^ (r & 7)) << 3)];
      vb11 = *(const bf16x8*)&Vs[cur][r][(((4 + lg) ^ (r & 7)) << 3)];
    }
    {
      int r = 32 + l15;
      vb20 = *(const bf16x8*)&Vs[cur][r][((lg ^ (r & 7)) << 3)];
      vb21 = *(const bf16x8*)&Vs[cur][r][(((4 + lg) ^ (r & 7)) << 3)];
    }
    {
      int r = 48 + l15;
      vb30 = *(const bf16x8*)&Vs[cur][r][((lg ^ (r & 7)) << 3)];
      vb31 = *(const bf16x8*)&Vs[cur][r][(((4 + lg) ^ (r & 7)) << 3)];
    }
    __builtin_amdgcn_s_setprio(1);
    o0 = __builtin_amdgcn_mfma_f32_16x16x32_bf16(pa0, vb00, o0, 0, 0, 0);
    o0 = __builtin_amdgcn_mfma_f32_16x16x32_bf16(pa1, vb01, o0, 0, 0, 0);
    o1 = __builtin_amdgcn_mfma_f32_16x16x32_bf16(pa0, vb10, o1, 0, 0, 0);
    o1 = __builtin_amdgcn_mfma_f32_16x16x32_bf16(pa1, vb11, o1, 0, 0, 0);
    o2 = __builtin_amdgcn_mfma_f32_16x16x32_bf16(pa0, vb20, o2, 0, 0, 0);
    o2 = __builtin_amdgcn_mfma_f32_16x16x32_bf16(pa1, vb21, o2, 0, 0, 0);
    o3 = __builtin_amdgcn_mfma_f32_16x16x32_bf16(pa0, vb30, o3, 0, 0, 0);
    o3 = __builtin_amdgcn_mfma_f32_16x16x32_bf16(pa1, vb31, o3, 0, 0, 0);
    __builtin_amdgcn_s_setprio(0);
  }

  // ---- epilogue: reduce l partials, normalize, residual, store ----
  int b = bh >> 3, h = bh & 7;
#pragma unroll
  for (int j = 0; j < 4; ++j) {
    int ql = w * 16 + lg * 4 + j;
    int qi = q0 + ql;
    float l = lrow[j];
    l += __shfl_xor(l, 1);
    l += __shfl_xor(l, 2);
    l += __shfl_xor(l, 4);
    l += __shfl_xor(l, 8);
    if (qi >= NOUT) continue;
    float inv = 1.f / l;
    float v0 = o0[j] * inv, v1 = o1[j] * inv, v2 = o2[j] * inv, v3 = o3[j] * inv;
    if (qi > 0) {
      const u16* qp2 = Q + base + (size_t)qi * DH;
      v0 += b2f(qp2[ 0 + l15]);
      v1 += b2f(qp2[16 + l15]);
      v2 += b2f(qp2[32 + l15]);
      v3 += b2f(qp2[48 + l15]);
    }
    size_t ob = ((size_t)b * NOUT + qi) * CDIM + h * DH;
    O[ob +  0 + l15] = f2b(v0);
    O[ob + 16 + l15] = f2b(v1);
    O[ob + 32 + l15] = f2b(v2);
    O[ob + 48 + l15] = f2b(v3);
  }
}

// ---------------------------------------------------------------------------
// ws layout (u16): s0..s4 (5 x PSZ), Wb (4 x WSZ), Rhb/Rwb (2 x 4096). ~34 MB.
// Schedule: pool: Pq->s0, Pk->s1, Pv->s2
//           mgemm3: s0->qbuf(Q), s1->s3(K), s2->s4(V)   [disjoint in/out]
//           fattn:  (qbuf,s3,s4) -> s0
//           proj:   s0 -> d_out (f32, overwrites qbuf; Q dead)
// ---------------------------------------------------------------------------
extern "C" void kernel_launch(void* const* d_in, const int* in_sizes, int n_in,
                              void* d_out, int out_size, void* d_ws, size_t ws_size,
                              hipStream_t stream) {
  const float* x     = (const float*)d_in[0];
  const float* xr    = (const float*)d_in[1];
  const float* wq    = (const float*)d_in[2];
  const float* bq    = (const float*)d_in[3];
  const float* wk    = (const float*)d_in[4];
  const float* bk    = (const float*)d_in[5];
  const float* wv    = (const float*)d_in[6];
  const float* bv    = (const float*)d_in[7];
  const float* wpj   = (const float*)d_in[8];
  const float* bpj   = (const float*)d_in[9];
  const float* cwq   = (const float*)d_in[10];
  const float* cwk   = (const float*)d_in[11];
  const float* cwv   = (const float*)d_in[12];
  const float* gq    = (const float*)d_in[13];
  const float* lbq   = (const float*)d_in[14];
  const float* gk    = (const float*)d_in[15];
  const float* lbk   = (const float*)d_in[16];
  const float* gv    = (const float*)d_in[17];
  const float* lbv   = (const float*)d_in[18];
  const float* rph   = (const float*)d_in[19];
  const float* rpw   = (const float*)d_in[20];
  (void)in_sizes; (void)n_in; (void)out_size; (void)ws_size;

  u16* ws = (u16*)d_ws;
  const size_t PSZ = (size_t)ROWS * CDIM;
  const size_t WSZ = (size_t)CDIM * CDIM;
  u16* s0 = ws + 0 * PSZ;
  u16* s1 = ws + 1 * PSZ;
  u16* s2 = ws + 2 * PSZ;
  u16* s3 = ws + 3 * PSZ;
  u16* s4 = ws + 4 * PSZ;
  u16* Wb  = ws + 5 * PSZ;
  u16* Rhb = Wb + 4 * WSZ;
  u16* Rwb = Rhb + 64 * 64;
  u16* qbuf = (u16*)d_out;              // bf16 scratch inside f32 output buffer

  // 1) pool + layernorm (float4-vectorized): Pq->s0, Pk->s1, Pv->s2
  pool_ln_kernel<<<dim3((NOUT + 1) / 2, 8, 2), 256, 0, stream>>>(
      x, xr, cwq, cwk, cwv, gq, lbq, gk, lbk, gv, lbv, s0, s1, s2);

  // 2) weights + rel_pos -> bf16 (fused; rel pre-scaled by log2e)
  cvt_kernel<<<1025, 256, 0, stream>>>(wq, wk, wv, wpj, rph, rpw, Wb, Rhb, Rwb);

  // 3) q/k/v projections: q: s0->qbuf, k: s1->s3, v: s2->s4
  dim3 g3((ROWS + 63) / 64, CDIM / 128, 3);
  mgemm3_kernel<<<g3, 256, 0, stream>>>(s0, s1, s2, Wb, bq, bk, bv, qbuf, s3, s4);

  // 4) attention -> s0
  fattn_kernel<<<NKT * 64, 256, 0, stream>>>(qbuf, s3, s4, Rhb, Rwb, s0);

  // 5) output projection -> f32 d_out
  dim3 gp((ROWS + 63) / 64, CDIM / 128);
  mgemm_proj_kernel<<<gp, 256, 0, stream>>>(s0, Wb + 3 * WSZ, bpj, (float*)d_out);
}

// Round 20
// 199.130 us; speedup vs baseline: 1.0328x; 1.0328x over previous
//
#include <hip/hip_runtime.h>

// Problem constants (B=8, T=1, H=56, C=512, nh=8, d=64)
// Inputs: float32. Output: float32. ws intermediates: bf16.
#define NH    8
#define DH    64
#define NTOK  3137      // 56*56+1
#define NOUT  785       // 28*28+1
#define CDIM  512
#define ROWS  6280      // 8*785
#define HO    28
#define HIN   56
#define NKT   13        // ceil(785/64) key tiles
#define RELD  55        // 2*(56//2)-1
#define LOG2E 1.4426950408889634f

typedef unsigned short u16;
typedef unsigned int u32;
typedef __attribute__((ext_vector_type(8))) short bf16x8;   // 8 bf16 = 4 VGPRs
typedef __attribute__((ext_vector_type(4))) float f32x4;    // MFMA C/D

__device__ __forceinline__ float b2f(u16 u) { return __uint_as_float(((u32)u) << 16); }
__device__ __forceinline__ u16 f2b(float f) {
  u32 u = __float_as_uint(f);
  return (u16)((u + 0x7FFFu + ((u >> 16) & 1u)) >> 16);
}

// ---------------------------------------------------------------------------
// Kernel 1: depthwise 3x3 stride-2 pool + LayerNorm(64), float4-vectorized.
// (verified R14)
// ---------------------------------------------------------------------------
__global__ __launch_bounds__(256) void pool_ln_kernel(
    const float* __restrict__ x, const float* __restrict__ xr,
    const float* __restrict__ cwq, const float* __restrict__ cwk, const float* __restrict__ cwv,
    const float* __restrict__ gq, const float* __restrict__ bq,
    const float* __restrict__ gk, const float* __restrict__ bk,
    const float* __restrict__ gv, const float* __restrict__ bv,
    u16* __restrict__ Pq, u16* __restrict__ Pk, u16* __restrict__ Pv)
{
  int tid   = threadIdx.x;
  int n     = blockIdx.x * 2 + (tid >> 7);           // token (wave-uniform half)
  int b     = blockIdx.y;
  int which = blockIdx.z;                            // 0=q(x), 1=k+v(x_ref)
  if (n >= NOUT) return;
  int c4 = tid & 127;
  int c  = c4 * 4;
  int d0 = c & 63;

  const float* src  = which ? xr : x;
  const float* srcb = src + (size_t)b * NTOK * CDIM + c;
  size_t obase = (size_t)(b * NOUT + n) * CDIM + c;

  float4 vq = make_float4(0.f, 0.f, 0.f, 0.f);
  float4 vk = make_float4(0.f, 0.f, 0.f, 0.f);
  const float* cw0 = which ? cwk : cwq;

  if (n == 0) {
    float4 t = *(const float4*)(srcb);
    vq = t; vk = t;
  } else {
    int oy = (n - 1) / HO, ox = (n - 1) % HO;
#pragma unroll
    for (int ky = 0; ky < 3; ++ky) {
      int iy = oy * 2 - 1 + ky;
      if (iy < 0 || iy >= HIN) continue;
#pragma unroll
      for (int kx = 0; kx < 3; ++kx) {
        int ix = ox * 2 - 1 + kx;
        if (ix < 0 || ix >= HIN) continue;
        int tok = 1 + iy * HIN + ix;
        float4 t  = *(const float4*)(srcb + (size_t)tok * CDIM);
        float4 w0 = *(const float4*)(cw0 + (ky * 3 + kx) * DH + d0);
        vq.x += t.x * w0.x; vq.y += t.y * w0.y; vq.z += t.z * w0.z; vq.w += t.w * w0.w;
        if (which) {
          float4 w1 = *(const float4*)(cwv + (ky * 3 + kx) * DH + d0);
          vk.x += t.x * w1.x; vk.y += t.y * w1.y; vk.z += t.z * w1.z; vk.w += t.w * w1.w;
        }
      }
    }
  }

  {
    float s  = vq.x + vq.y + vq.z + vq.w;
    float sq = vq.x * vq.x + vq.y * vq.y + vq.z * vq.z + vq.w * vq.w;
#pragma unroll
    for (int off = 1; off < 16; off <<= 1) {
      s  += __shfl_xor(s, off, 64);
      sq += __shfl_xor(sq, off, 64);
    }
    float mu  = s * (1.f / 64.f);
    float var = sq * (1.f / 64.f) - mu * mu;
    float inv = rsqrtf(var + 1e-5f);
    const float* g  = which ? gk : gq;
    const float* be = which ? bk : bq;
    float4 gg = *(const float4*)(g + d0);
    float4 bb = *(const float4*)(be + d0);
    ushort4 o;
    o.x = f2b((vq.x - mu) * inv * gg.x + bb.x);
    o.y = f2b((vq.y - mu) * inv * gg.y + bb.y);
    o.z = f2b((vq.z - mu) * inv * gg.z + bb.z);
    o.w = f2b((vq.w - mu) * inv * gg.w + bb.w);
    *(ushort4*)(((which ? Pk : Pq)) + obase) = o;
  }
  if (which) {
    float s  = vk.x + vk.y + vk.z + vk.w;
    float sq = vk.x * vk.x + vk.y * vk.y + vk.z * vk.z + vk.w * vk.w;
#pragma unroll
    for (int off = 1; off < 16; off <<= 1) {
      s  += __shfl_xor(s, off, 64);
      sq += __shfl_xor(sq, off, 64);
    }
    float mu  = s * (1.f / 64.f);
    float var = sq * (1.f / 64.f) - mu * mu;
    float inv = rsqrtf(var + 1e-5f);
    float4 gg = *(const float4*)(gv + d0);
    float4 bb = *(const float4*)(bv + d0);
    ushort4 o;
    o.x = f2b((vk.x - mu) * inv * gg.x + bb.x);
    o.y = f2b((vk.y - mu) * inv * gg.y + bb.y);
    o.z = f2b((vk.z - mu) * inv * gg.z + bb.z);
    o.w = f2b((vk.w - mu) * inv * gg.w + bb.w);
    *(ushort4*)(Pv + obase) = o;
  }
}

// ---------------------------------------------------------------------------
// Kernel 2a: convert the four 512x512 f32 weight matrices to bf16 (packed).
// (separate kernel — fusing rcvt into this cost ~8 us of serial tail, R18/R19)
// ---------------------------------------------------------------------------
__global__ __launch_bounds__(256) void wcvt_kernel(
    const float* __restrict__ W0, const float* __restrict__ W1,
    const float* __restrict__ W2, const float* __restrict__ W3,
    u16* __restrict__ out)
{
  int idx = blockIdx.x * blockDim.x + threadIdx.x;
  const int per = CDIM * CDIM / 4;
  int mat = idx / per, off = (idx - mat * per) * 4;
  const float* src = (mat == 0) ? W0 : (mat == 1) ? W1 : (mat == 2) ? W2 : W3;
  float4 v = *(const float4*)(src + off);
  ushort4 o;
  o.x = f2b(v.x); o.y = f2b(v.y); o.z = f2b(v.z); o.w = f2b(v.w);
  *(ushort4*)(out + (size_t)mat * (CDIM * CDIM) + off) = o;
}

// ---------------------------------------------------------------------------
// Kernel 2b: rel_pos f32 (55x64) -> bf16 padded [64][64], PRE-SCALED by log2e.
// ---------------------------------------------------------------------------
__global__ __launch_bounds__(256) void rcvt_kernel(
    const float* __restrict__ rph, const float* __restrict__ rpw,
    u16* __restrict__ Rhb, u16* __restrict__ Rwb)
{
  int idx = blockIdx.x * blockDim.x + threadIdx.x;
  if (idx >= 64 * 64) return;
  int r = idx >> 6, d = idx & 63;
  Rhb[idx] = (r < RELD) ? f2b(rph[r * DH + d] * LOG2E) : 0;
  Rwb[idx] = (r < RELD) ? f2b(rpw[r * DH + d] * LOG2E) : 0;
}

// ---------------------------------------------------------------------------
// Kernel 3a: batched MFMA GEMM for q/k/v. Tile 64x128 (wave 32x64). (R15 form)
// ---------------------------------------------------------------------------
__global__ __launch_bounds__(256) void mgemm3_kernel(
    const u16* __restrict__ Xq, const u16* __restrict__ Xk, const u16* __restrict__ Xv,
    const u16* __restrict__ Wb, const float* __restrict__ bq,
    const float* __restrict__ bk, const float* __restrict__ bv,
    u16* __restrict__ Yq, u16* __restrict__ Yk, u16* __restrict__ Yv)
{
  int z = blockIdx.z;
  const u16* X = (z == 0) ? Xq : (z == 1) ? Xk : Xv;
  const u16* W = Wb + (size_t)z * CDIM * CDIM;
  const float* bias = (z == 0) ? bq : (z == 1) ? bk : bv;
  u16* Y = (z == 0) ? Yq : (z == 1) ? Yk : Yv;

  int tid = threadIdx.x;
  int w = tid >> 6, lane = tid & 63, l15 = lane & 15, lg = lane >> 4;
  int m0 = blockIdx.x * 64 + (w >> 1) * 32;
  int n0 = blockIdx.y * 128 + (w & 1) * 64;

  f32x4 acc[2][4] = {};
  float bs[4];
#pragma unroll
  for (int nf = 0; nf < 4; ++nf) bs[nf] = bias[n0 + nf * 16 + l15];

  for (int k0 = 0; k0 < CDIM; k0 += 32) {
    bf16x8 a[2], b[4];
#pragma unroll
    for (int mf = 0; mf < 2; ++mf) {
      int r = m0 + mf * 16 + l15;
      if (r > ROWS - 1) r = ROWS - 1;
      a[mf] = *(const bf16x8*)(X + (size_t)r * CDIM + k0 + lg * 8);
    }
#pragma unroll
    for (int nf = 0; nf < 4; ++nf) {
      int co = n0 + nf * 16 + l15;
      b[nf] = *(const bf16x8*)(W + (size_t)co * CDIM + k0 + lg * 8);
    }
#pragma unroll
    for (int mf = 0; mf < 2; ++mf)
#pragma unroll
      for (int nf = 0; nf < 4; ++nf)
        acc[mf][nf] = __builtin_amdgcn_mfma_f32_16x16x32_bf16(a[mf], b[nf], acc[mf][nf], 0, 0, 0);
  }

#pragma unroll
  for (int mf = 0; mf < 2; ++mf) {
#pragma unroll
    for (int j = 0; j < 4; ++j) {
      int r = m0 + mf * 16 + lg * 4 + j;
      if (r >= ROWS) continue;
      int bb = r / NOUT, n = r % NOUT;
#pragma unroll
      for (int nf = 0; nf < 4; ++nf) {
        int co = n0 + nf * 16 + l15;
        float v = acc[mf][nf][j] + bs[nf];
        Y[(((size_t)bb * NH + (co >> 6)) * NOUT + n) * DH + (co & 63)] = f2b(v);
      }
    }
  }
}

// ---------------------------------------------------------------------------
// Kernel 3b: proj MFMA GEMM, 64x128 tile -> f32 row-major d_out. (R15 form)
// ---------------------------------------------------------------------------
__global__ __launch_bounds__(256) void mgemm_proj_kernel(
    const u16* __restrict__ X, const u16* __restrict__ Wb, const float* __restrict__ bias,
    float* __restrict__ Y)
{
  int tid = threadIdx.x;
  int w = tid >> 6, lane = tid & 63, l15 = lane & 15, lg = lane >> 4;
  int m0 = blockIdx.x * 64 + (w >> 1) * 32;
  int n0 = blockIdx.y * 128 + (w & 1) * 64;

  f32x4 acc[2][4] = {};
  float bs[4];
#pragma unroll
  for (int nf = 0; nf < 4; ++nf) bs[nf] = bias[n0 + nf * 16 + l15];

  for (int k0 = 0; k0 < CDIM; k0 += 32) {
    bf16x8 a[2], b[4];
#pragma unroll
    for (int mf = 0; mf < 2; ++mf) {
      int r = m0 + mf * 16 + l15;
      if (r > ROWS - 1) r = ROWS - 1;
      a[mf] = *(const bf16x8*)(X + (size_t)r * CDIM + k0 + lg * 8);
    }
#pragma unroll
    for (int nf = 0; nf < 4; ++nf) {
      int co = n0 + nf * 16 + l15;
      b[nf] = *(const bf16x8*)(Wb + (size_t)co * CDIM + k0 + lg * 8);
    }
#pragma unroll
    for (int mf = 0; mf < 2; ++mf)
#pragma unroll
      for (int nf = 0; nf < 4; ++nf)
        acc[mf][nf] = __builtin_amdgcn_mfma_f32_16x16x32_bf16(a[mf], b[nf], acc[mf][nf], 0, 0, 0);
  }

#pragma unroll
  for (int mf = 0; mf < 2; ++mf) {
#pragma unroll
    for (int j = 0; j < 4; ++j) {
      int r = m0 + mf * 16 + lg * 4 + j;
      if (r >= ROWS) continue;
#pragma unroll
      for (int nf = 0; nf < 4; ++nf) {
        int co = n0 + nf * 16 + l15;
        Y[(size_t)r * CDIM + co] = acc[mf][nf][j] + bs[nf];
      }
    }
  }
}

// ---------------------------------------------------------------------------
// Kernel 4: flash-style MFMA attention — verified 80.5 us stable form:
// per-tile K loads before V prefetch, packed-u32 V stage, setprio around MFMA
// clusters, exp2-domain softmax, deferred l-reduce, incremental ky/kx.
// ---------------------------------------------------------------------------
__global__ __launch_bounds__(256, 4) void fattn_kernel(
    const u16* __restrict__ Q, const u16* __restrict__ K, const u16* __restrict__ V,
    const u16* __restrict__ Rhb, const u16* __restrict__ Rwb,
    u16* __restrict__ O)
{
  __shared__ u16 Vs[2][64][64];     // [buf][d][k] XOR-swizzled      16384 B
  __shared__ u16 Ps[4][16][72];     // per-wave P bounce              9216 B
  __shared__ u16 relh[64][RELD];    // G_h[q][r]  (log2e-scaled)      7040 B
  __shared__ u16 relw[64][RELD];    //                                7040 B

  int bid = blockIdx.x;
  int nbid = (bid & 7) * 104 + (bid >> 3);
  int bh = nbid / NKT, qt = nbid % NKT;

  int tid = threadIdx.x;
  int w = tid >> 6, lane = tid & 63, l15 = lane & 15, lg = lane >> 4;
  size_t base = (size_t)bh * NOUT * DH;
  int q0 = qt * 64;

  // V-stage geometry: thread <-> (key pair, 8-d block)
  int vkp = (tid & 31) * 2;         // even key in tile (0..62)
  int vdb = (tid >> 5) * 8;         // d0 (0..56)

  // ---- Q A-fragments direct from global ----
  int qrow_qi = min(q0 + w * 16 + l15, NOUT - 1);
  const u16* qp = Q + base + (size_t)qrow_qi * DH + lg * 8;
  bf16x8 qa0 = *(const bf16x8*)(qp);
  bf16x8 qa1 = *(const bf16x8*)(qp + 32);

  // ---- prologue V stage: tile 0 -> Vs[0] (packed u32 writes) ----
  {
    int ke = min(vkp, NOUT - 1), ko = min(vkp + 1, NOUT - 1);
    bf16x8 ve = *(const bf16x8*)(V + base + (size_t)ke * DH + vdb);
    bf16x8 vo = *(const bf16x8*)(V + base + (size_t)ko * DH + vdb);
#pragma unroll
    for (int i = 0; i < 8; ++i) {
      int d = vdb + i;
      int col = ((((vkp >> 3) ^ (d & 7)) << 3) | (vkp & 7));
      u32 pk = (u32)(u16)ve[i] | ((u32)(u16)vo[i] << 16);
      *(u32*)&Vs[0][d][col] = pk;
    }
  }

  // ---- rel-pos tables via MFMA (wave-private rows, log2e-scaled) ----
#pragma unroll
  for (int nf = 0; nf < 4; ++nf) {
    int rr = nf * 16 + l15;
    const u16* hp = Rhb + rr * 64 + lg * 8;
    bf16x8 hb0 = *(const bf16x8*)(hp);
    bf16x8 hb1 = *(const bf16x8*)(hp + 32);
    f32x4 ah = {};
    ah = __builtin_amdgcn_mfma_f32_16x16x32_bf16(qa0, hb0, ah, 0, 0, 0);
    ah = __builtin_amdgcn_mfma_f32_16x16x32_bf16(qa1, hb1, ah, 0, 0, 0);
    const u16* wp = Rwb + rr * 64 + lg * 8;
    bf16x8 wb0 = *(const bf16x8*)(wp);
    bf16x8 wb1 = *(const bf16x8*)(wp + 32);
    f32x4 aw = {};
    aw = __builtin_amdgcn_mfma_f32_16x16x32_bf16(qa0, wb0, aw, 0, 0, 0);
    aw = __builtin_amdgcn_mfma_f32_16x16x32_bf16(qa1, wb1, aw, 0, 0, 0);
    if (rr < RELD) {
#pragma unroll
      for (int j = 0; j < 4; ++j) {
        relh[w * 16 + lg * 4 + j][rr] = f2b(ah[j]);
        relw[w * 16 + lg * 4 + j][rr] = f2b(aw[j]);
      }
    }
  }

  // ---- per-j query geometry ----
  int qy_j[4], qx_j[4];
  bool qv_j[4];
#pragma unroll
  for (int j = 0; j < 4; ++j) {
    int qi = q0 + w * 16 + lg * 4 + j;
    qv_j[j] = (qi >= 1);
    int qm1 = qi - 1;
    qy_j[j] = qm1 / HO;
    qx_j[j] = qm1 % HO;
  }

  // ---- incremental key geometry per sub ----
  int kyr[4], kxr[4];
#pragma unroll
  for (int sub = 0; sub < 4; ++sub) {
    int km1 = sub * 16 + l15 - 1;   // -1 only for (sub=0,l15=0): unused (key<1)
    kyr[sub] = km1 / HO;
    kxr[sub] = km1 % HO;
  }

  f32x4 o0 = {}, o1 = {}, o2 = {}, o3 = {};
  float mrow[4], lrow[4];
#pragma unroll
  for (int j = 0; j < 4; ++j) { mrow[j] = -1e30f; lrow[j] = 0.f; }

  const float QKSCALE = 0.125f * LOG2E;

  for (int t = 0; t < NKT; ++t) {
    int k0 = t * 64;
    int cur = t & 1;
    __syncthreads();   // Vs[cur] fully staged; prev tile's PV reads done

    // ---- K fragment loads FIRST (oldest in vm queue) ----
    bf16x8 kb[4][2];
#pragma unroll
    for (int sub = 0; sub < 4; ++sub) {
      int key = k0 + sub * 16 + l15;
      int keff = min(key, NOUT - 1);
      const u16* kp = K + base + (size_t)keff * DH + lg * 8;
      kb[sub][0] = *(const bf16x8*)(kp);
      kb[sub][1] = *(const bf16x8*)(kp + 32);
    }

    // ---- THEN issue next V tile's loads ----
    bf16x8 nve, nvo;
    bool have_next = (t + 1 < NKT);
    if (have_next) {
      int ke = min(k0 + 64 + vkp, NOUT - 1), ko = min(k0 + 64 + vkp + 1, NOUT - 1);
      nve = *(const bf16x8*)(V + base + (size_t)ke * DH + vdb);
      nvo = *(const bf16x8*)(V + base + (size_t)ko * DH + vdb);
    }

    // ---- S = scale*Q.K^T + bias   (log2 domain) ----
    f32x4 s[4];
    __builtin_amdgcn_s_setprio(1);
#pragma unroll
    for (int sub = 0; sub < 4; ++sub) {
      f32x4 acc = {};
      acc = __builtin_amdgcn_mfma_f32_16x16x32_bf16(qa0, kb[sub][0], acc, 0, 0, 0);
      acc = __builtin_amdgcn_mfma_f32_16x16x32_bf16(qa1, kb[sub][1], acc, 0, 0, 0);
      s[sub] = acc;
    }
    __builtin_amdgcn_s_setprio(0);
#pragma unroll
    for (int sub = 0; sub < 4; ++sub) {
      int key = k0 + sub * 16 + l15;
      bool kv = key < NOUT;
      int ky = kyr[sub], kx = kxr[sub];
#pragma unroll
      for (int j = 0; j < 4; ++j) {
        float v = s[sub][j] * QKSCALE;
        if (key >= 1 && kv && qv_j[j]) {
          int ql = w * 16 + lg * 4 + j;
          v += b2f(relh[ql][qy_j[j] - ky + 27]) + b2f(relw[ql][qx_j[j] - kx + 27]);
        }
        if (!kv) v = -1e30f;
        s[sub][j] = v;
      }
    }

    // ---- advance key geometry (+64 keys = +2 rows +8 cols, carry) ----
#pragma unroll
    for (int sub = 0; sub < 4; ++sub) {
      kxr[sub] += 8; kyr[sub] += 2;
      if (kxr[sub] >= HO) { kxr[sub] -= HO; kyr[sub] += 1; }
    }

    // ---- online softmax (exp2 domain; per-lane l partials) ----
#pragma unroll
    for (int j = 0; j < 4; ++j) {
      float lm = fmaxf(fmaxf(s[0][j], s[1][j]), fmaxf(s[2][j], s[3][j]));
      lm = fmaxf(lm, __shfl_xor(lm, 1));
      lm = fmaxf(lm, __shfl_xor(lm, 2));
      lm = fmaxf(lm, __shfl_xor(lm, 4));
      lm = fmaxf(lm, __shfl_xor(lm, 8));
      if (lm > mrow[j]) {
        float a = exp2f(mrow[j] - lm);
        mrow[j] = lm;
        o0[j] *= a; o1[j] *= a; o2[j] *= a; o3[j] *= a;
        lrow[j] *= a;
      }
      float ps = 0.f;
#pragma unroll
      for (int sub = 0; sub < 4; ++sub) {
        float pv = exp2f(s[sub][j] - mrow[j]);
        s[sub][j] = pv;
        ps += pv;
      }
      lrow[j] += ps;
    }

    // ---- write next V tile into idle buffer (packed u32; no barrier) ----
    if (have_next) {
#pragma unroll
      for (int i = 0; i < 8; ++i) {
        int d = vdb + i;
        int col = ((((vkp >> 3) ^ (d & 7)) << 3) | (vkp & 7));
        u32 pk = (u32)(u16)nve[i] | ((u32)(u16)nvo[i] << 16);
        *(u32*)&Vs[cur ^ 1][d][col] = pk;
      }
    }

    // ---- bounce P (wave-private) ----
#pragma unroll
    for (int j = 0; j < 4; ++j) {
      Ps[w][lg * 4 + j][ 0 + l15] = f2b(s[0][j]);
      Ps[w][lg * 4 + j][16 + l15] = f2b(s[1][j]);
      Ps[w][lg * 4 + j][32 + l15] = f2b(s[2][j]);
      Ps[w][lg * 4 + j][48 + l15] = f2b(s[3][j]);
    }

    // ---- O += P.V from Vs[cur] ----
    bf16x8 pa0 = *(const bf16x8*)&Ps[w][l15][lg * 8];
    bf16x8 pa1 = *(const bf16x8*)&Ps[w][l15][32 + lg * 8];
    bf16x8 vb00, vb01, vb10, vb11, vb20, vb21, vb30, vb31;
    {
      int r = 0 + l15;
      vb00 = *(const bf16x8*)&Vs[cur][r][((lg ^ (r & 7)) << 3)];
      vb01 = *(const bf16x8*)&Vs[cur][r][(((4 + lg) ^ (r & 7)) << 3)];
    }
    {
      int r = 16 + l15;
      vb10 = *(const bf16x8*)&Vs[cur][r][((lg ^ (r & 7)) << 3)];
      vb11 = *(const bf16x8*)&Vs[cur][r][(((4 + lg) ^ (r & 7)) << 3)];
    }
    {
      int r = 32 + l15;
      vb20 = *(const bf16x8*)&Vs[cur][r][((lg ^ (r & 7)) << 3)];
      vb21 = *(const bf16x8*)&Vs[cur][r][(((4 + lg) ^ (r & 7)) << 3)];
    }
    {
      int r = 48 + l15;
      vb30 = *(const bf16x8*)&Vs[cur][r][((lg ^ (r & 7)) << 3)];
      vb31 = *(const bf16x8*)&Vs[cur][r][(((4 + lg) ^ (r & 7)) << 3)];
    }
    __builtin_amdgcn_s_setprio(1);
    o0 = __builtin_amdgcn_mfma_f32_16x16x32_bf16(pa0, vb00, o0, 0, 0, 0);
    o0 = __builtin_amdgcn_mfma_f32_16x16x32_bf16(pa1, vb01, o0, 0, 0, 0);
    o1 = __builtin_amdgcn_mfma_f32_16x16x32_bf16(pa0, vb10, o1, 0, 0, 0);
    o1 = __builtin_amdgcn_mfma_f32_16x16x32_bf16(pa1, vb11, o1, 0, 0, 0);
    o2 = __builtin_amdgcn_mfma_f32_16x16x32_bf16(pa0, vb20, o2, 0, 0, 0);
    o2 = __builtin_amdgcn_mfma_f32_16x16x32_bf16(pa1, vb21, o2, 0, 0, 0);
    o3 = __builtin_amdgcn_mfma_f32_16x16x32_bf16(pa0, vb30, o3, 0, 0, 0);
    o3 = __builtin_amdgcn_mfma_f32_16x16x32_bf16(pa1, vb31, o3, 0, 0, 0);
    __builtin_amdgcn_s_setprio(0);
  }

  // ---- epilogue: reduce l partials, normalize, residual, store ----
  int b = bh >> 3, h = bh & 7;
#pragma unroll
  for (int j = 0; j < 4; ++j) {
    int ql = w * 16 + lg * 4 + j;
    int qi = q0 + ql;
    float l = lrow[j];
    l += __shfl_xor(l, 1);
    l += __shfl_xor(l, 2);
    l += __shfl_xor(l, 4);
    l += __shfl_xor(l, 8);
    if (qi >= NOUT) continue;
    float inv = 1.f / l;
    float v0 = o0[j] * inv, v1 = o1[j] * inv, v2 = o2[j] * inv, v3 = o3[j] * inv;
    if (qi > 0) {
      const u16* qp2 = Q + base + (size_t)qi * DH;
      v0 += b2f(qp2[ 0 + l15]);
      v1 += b2f(qp2[16 + l15]);
      v2 += b2f(qp2[32 + l15]);
      v3 += b2f(qp2[48 + l15]);
    }
    size_t ob = ((size_t)b * NOUT + qi) * CDIM + h * DH;
    O[ob +  0 + l15] = f2b(v0);
    O[ob + 16 + l15] = f2b(v1);
    O[ob + 32 + l15] = f2b(v2);
    O[ob + 48 + l15] = f2b(v3);
  }
}

// ---------------------------------------------------------------------------
// ws layout (u16): s0..s4 (5 x PSZ), Wb (4 x WSZ), Rhb/Rwb (2 x 4096). ~34 MB.
// Schedule: pool: Pq->s0, Pk->s1, Pv->s2
//           mgemm3: s0->qbuf(Q), s1->s3(K), s2->s4(V)   [disjoint in/out]
//           fattn:  (qbuf,s3,s4) -> s0
//           proj:   s0 -> d_out (f32, overwrites qbuf; Q dead)
// ---------------------------------------------------------------------------
extern "C" void kernel_launch(void* const* d_in, const int* in_sizes, int n_in,
                              void* d_out, int out_size, void* d_ws, size_t ws_size,
                              hipStream_t stream) {
  const float* x     = (const float*)d_in[0];
  const float* xr    = (const float*)d_in[1];
  const float* wq    = (const float*)d_in[2];
  const float* bq    = (const float*)d_in[3];
  const float* wk    = (const float*)d_in[4];
  const float* bk    = (const float*)d_in[5];
  const float* wv    = (const float*)d_in[6];
  const float* bv    = (const float*)d_in[7];
  const float* wpj   = (const float*)d_in[8];
  const float* bpj   = (const float*)d_in[9];
  const float* cwq   = (const float*)d_in[10];
  const float* cwk   = (const float*)d_in[11];
  const float* cwv   = (const float*)d_in[12];
  const float* gq    = (const float*)d_in[13];
  const float* lbq   = (const float*)d_in[14];
  const float* gk    = (const float*)d_in[15];
  const float* lbk   = (const float*)d_in[16];
  const float* gv    = (const float*)d_in[17];
  const float* lbv   = (const float*)d_in[18];
  const float* rph   = (const float*)d_in[19];
  const float* rpw   = (const float*)d_in[20];
  (void)in_sizes; (void)n_in; (void)out_size; (void)ws_size;

  u16* ws = (u16*)d_ws;
  const size_t PSZ = (size_t)ROWS * CDIM;
  const size_t WSZ = (size_t)CDIM * CDIM;
  u16* s0 = ws + 0 * PSZ;
  u16* s1 = ws + 1 * PSZ;
  u16* s2 = ws + 2 * PSZ;
  u16* s3 = ws + 3 * PSZ;
  u16* s4 = ws + 4 * PSZ;
  u16* Wb  = ws + 5 * PSZ;
  u16* Rhb = Wb + 4 * WSZ;
  u16* Rwb = Rhb + 64 * 64;
  u16* qbuf = (u16*)d_out;              // bf16 scratch inside f32 output buffer

  // 1) pool + layernorm (float4-vectorized): Pq->s0, Pk->s1, Pv->s2
  pool_ln_kernel<<<dim3((NOUT + 1) / 2, 8, 2), 256, 0, stream>>>(
      x, xr, cwq, cwk, cwv, gq, lbq, gk, lbk, gv, lbv, s0, s1, s2);

  // 2) weights + rel_pos -> bf16 (separate kernels: parallel, short tail)
  wcvt_kernel<<<(4 * CDIM * CDIM / 4 + 255) / 256, 256, 0, stream>>>(wq, wk, wv, wpj, Wb);
  rcvt_kernel<<<16, 256, 0, stream>>>(rph, rpw, Rhb, Rwb);

  // 3) q/k/v projections: q: s0->qbuf, k: s1->s3, v: s2->s4
  dim3 g3((ROWS + 63) / 64, CDIM / 128, 3);
  mgemm3_kernel<<<g3, 256, 0, stream>>>(s0, s1, s2, Wb, bq, bk, bv, qbuf, s3, s4);

  // 4) attention -> s0
  fattn_kernel<<<NKT * 64, 256, 0, stream>>>(qbuf, s3, s4, Rhb, Rwb, s0);

  // 5) output projection -> f32 d_out
  dim3 gp((ROWS + 63) / 64, CDIM / 128);
  mgemm_proj_kernel<<<gp, 256, 0, stream>>>(s0, Wb + 3 * WSZ, bpj, (float*)d_out);
}